// Round 8
// baseline (155.091 us; speedup 1.0000x reference)
//
#include <hip/hip_runtime.h>
#include <hip/hip_fp16.h>

#define DIN 128
#define DOUT 32
#define SLOPE 0.2f

#define BSHIFT 7                 // 128 nodes per bucket
#define BNODES 128
#define NBS    1024              // scan width (>= 782 buckets, pow2)
#define CAP    3072              // record capacity (lambda 2046, +22 sigma)
#define SRTCAP (CAP + 384)       // node-sorted array, 4-aligned segments
#define TILE   4096              // edges per bin block (391 bin blocks)
#define EPB    (TILE / 256)      // edges per thread (16)
#define TPW    4                 // row-tiles per linear wave (W converted once)

typedef short s16x8 __attribute__((ext_vector_type(8)));   // 8 bf16 (4 VGPRs)
typedef float f32x4 __attribute__((ext_vector_type(4)));   // MFMA C/D frag

__device__ __forceinline__ short f2bf(float f) {          // fp32 -> bf16 (RNE)
    unsigned u = __float_as_uint(f);
    return (short)((u + 0x7fffu + ((u >> 16) & 1u)) >> 16);
}
__device__ __forceinline__ float bf2f(short s) {
    return __uint_as_float(((unsigned)(unsigned short)s) << 16);
}

// ---------------- Linear role: one wave = TPW x 16 rows of h via MFMA --------
// W converted once per wave. x is software-pipelined across the TPW loop
// (T14): kc0-1 of the NEXT tile prefetched during the current tile's compute;
// kc2-3 of the current tile issued at iteration top (latency hidden under
// kc0-1's convert+MFMA). R7's serial 4x(load-lat + compute) chain was the
// linear straggler (occupancy 18.5%, VALUBusy 12.5% -> latency-bound).
__device__ __forceinline__ void linear_role(
    int wid, int ntiles, int lane, int N,
    const float* __restrict__ x, const float* __restrict__ W,
    const float* __restrict__ b, const float* __restrict__ a2,
    __half* __restrict__ g16, float* __restrict__ es2)
{
    if (wid * TPW >= ntiles) return;
    int m = lane & 15, oct = lane >> 4;

    s16x8 bh[2][4], bl[2][4];
    #pragma unroll
    for (int t = 0; t < 2; ++t) {
        const float* wrow = W + (long)(t * 16 + m) * DIN + oct * 8;
        #pragma unroll
        for (int kc = 0; kc < 4; ++kc) {
            float4 w0 = *(const float4*)(wrow + kc * 32);
            float4 w1 = *(const float4*)(wrow + kc * 32 + 4);
            float wf[8] = {w0.x, w0.y, w0.z, w0.w, w1.x, w1.y, w1.z, w1.w};
            #pragma unroll
            for (int j = 0; j < 8; ++j) {
                short hh = f2bf(wf[j]);
                bh[t][kc][j] = hh;
                bl[t][kc][j] = f2bf(wf[j] - bf2f(hh));
            }
        }
    }

    int c0 = m, c1 = 16 + m;
    float b0 = b[c0], b1 = b[c1], A0 = a2[c0], A1 = a2[c1];

    float4 cxa[4];                              // current tile, kc0-1
    {
        long lrow = (long)(wid * TPW) * 16 + m; if (lrow > N - 1) lrow = N - 1;
        const float* xrow = x + lrow * DIN + oct * 8;
        #pragma unroll
        for (int kc = 0; kc < 2; ++kc) {
            cxa[2 * kc]     = *(const float4*)(xrow + kc * 32);
            cxa[2 * kc + 1] = *(const float4*)(xrow + kc * 32 + 4);
        }
    }

    #pragma unroll 1                           // sequential: keep VGPRs flat
    for (int g = 0; g < TPW; ++g) {
        int tile = wid * TPW + g;
        if (tile >= ntiles) break;
        long rowbase = (long)tile * 16;
        long lrow = rowbase + m; if (lrow > N - 1) lrow = N - 1;
        const float* xrow = x + lrow * DIN + oct * 8;

        float4 cxb[4];                          // current tile, kc2-3 (issue now)
        #pragma unroll
        for (int kc = 0; kc < 2; ++kc) {
            cxb[2 * kc]     = *(const float4*)(xrow + (kc + 2) * 32);
            cxb[2 * kc + 1] = *(const float4*)(xrow + (kc + 2) * 32 + 4);
        }

        bool hasnext = (g + 1 < TPW) && (tile + 1 < ntiles);
        float4 nxa[4];                          // next tile, kc0-1 (prefetch)
        if (hasnext) {
            long nrow = rowbase + 16 + m; if (nrow > N - 1) nrow = N - 1;
            const float* nx = x + nrow * DIN + oct * 8;
            #pragma unroll
            for (int kc = 0; kc < 2; ++kc) {
                nxa[2 * kc]     = *(const float4*)(nx + kc * 32);
                nxa[2 * kc + 1] = *(const float4*)(nx + kc * 32 + 4);
            }
        }

        f32x4 acc0 = {0.f, 0.f, 0.f, 0.f}, acc1 = {0.f, 0.f, 0.f, 0.f};
        #pragma unroll
        for (int kc = 0; kc < 4; ++kc) {
            float4 x0 = (kc < 2) ? cxa[2 * kc]     : cxb[2 * (kc - 2)];
            float4 x1 = (kc < 2) ? cxa[2 * kc + 1] : cxb[2 * (kc - 2) + 1];
            float xf[8] = {x0.x, x0.y, x0.z, x0.w, x1.x, x1.y, x1.z, x1.w};
            s16x8 ah, al;
            #pragma unroll
            for (int j = 0; j < 8; ++j) {
                short hh = f2bf(xf[j]);
                ah[j] = hh;
                al[j] = f2bf(xf[j] - bf2f(hh));
            }
            acc0 = __builtin_amdgcn_mfma_f32_16x16x32_bf16(al, bh[0][kc], acc0, 0, 0, 0);
            acc0 = __builtin_amdgcn_mfma_f32_16x16x32_bf16(ah, bl[0][kc], acc0, 0, 0, 0);
            acc0 = __builtin_amdgcn_mfma_f32_16x16x32_bf16(ah, bh[0][kc], acc0, 0, 0, 0);
            acc1 = __builtin_amdgcn_mfma_f32_16x16x32_bf16(al, bh[1][kc], acc1, 0, 0, 0);
            acc1 = __builtin_amdgcn_mfma_f32_16x16x32_bf16(ah, bl[1][kc], acc1, 0, 0, 0);
            acc1 = __builtin_amdgcn_mfma_f32_16x16x32_bf16(ah, bh[1][kc], acc1, 0, 0, 0);
        }

        float hv0[4], hv1[4], sp[4];
        #pragma unroll
        for (int i = 0; i < 4; ++i) {
            hv0[i] = acc0[i] + b0;
            hv1[i] = acc1[i] + b1;
            float z0 = hv0[i] > 0.f ? hv0[i] : SLOPE * hv0[i];
            float z1 = hv1[i] > 0.f ? hv1[i] : SLOPE * hv1[i];
            sp[i] = z0 * A0 + z1 * A1;
        }
        #pragma unroll
        for (int off = 1; off <= 8; off <<= 1) {
            #pragma unroll
            for (int i = 0; i < 4; ++i) sp[i] += __shfl_xor(sp[i], off, 64);
        }
        #pragma unroll
        for (int i = 0; i < 4; ++i) {
            long r = rowbase + oct * 4 + i;
            if (r >= N) continue;
            float ev = __expf(sp[i]);          // shift-invariant softmax: no max pass
            g16[r * DOUT + c0] = __float2half(ev * hv0[i]);
            g16[r * DOUT + c1] = __float2half(ev * hv1[i]);
            if (m == 0) es2[r] = ev;
        }
        if (hasnext) {
            #pragma unroll
            for (int i = 0; i < 4; ++i) cxa[i] = nxa[i];
        }
    }
}

// ---------------- Fused kernel: bin blocks FIRST, linear blocks fill in ------
// ZERO global atomics (verified R4). Each bin block counting-sorts its TILE
// edges by bucket into its PRIVATE slab ebuf[block*TILE ..] and writes the
// offset table TRANSPOSED: boffT[bucket][block] (coalesced aggregate reads).
__global__ __launch_bounds__(256) void gat_fused(
    const float* __restrict__ x, const float* __restrict__ W,
    const float* __restrict__ b, const float* __restrict__ a2,
    const int* __restrict__ src, const int* __restrict__ dst,
    __half* __restrict__ g16, float* __restrict__ es2,
    unsigned* __restrict__ ebuf, int* __restrict__ boffT,
    int N, int E, int ntiles, int nbin, int nbinp)
{
    if ((int)blockIdx.x >= nbin) {
        int wave = threadIdx.x >> 6;
        int wid = (blockIdx.x - nbin) * 4 + wave;
        linear_role(wid, ntiles, threadIdx.x & 63, N, x, W, b, a2, g16, es2);
        return;
    }
    __shared__ int cnt[NBS];     // 4 KB (buckets 782..1023 stay zero)
    __shared__ int offs[NBS];    // 4 KB exclusive scan
    __shared__ int wsum[4], wbase[4];
    int tid = threadIdx.x;
    long tstart = (long)blockIdx.x * TILE;

    for (int i = tid; i < NBS; i += 256) cnt[i] = 0;
    __syncthreads();

    unsigned rec[EPB];     // packed record (slot<<17 | dst)
    int      bq[EPB];      // bk<<9 | rank  (per-block per-bucket rank, lambda 5.2)
    #pragma unroll
    for (int it = 0; it < EPB; ++it) {         // pass 1: histogram + rank
        long e = tstart + it * 256 + tid;
        int s = (e < E) ? src[e] : -1;
        int d = (e < E) ? dst[e] : 0;          // prefetch (latency hides here)
        if (s >= 0) {
            int bk = s >> BSHIFT;
            int rv = atomicAdd(&cnt[bk], 1);   // native ds_add_rtn_u32
            rec[it] = ((unsigned)(s & (BNODES - 1)) << 17) | (unsigned)d;
            bq[it] = (rv < 511) ? ((bk << 9) | rv) : -1;   // 9-bit rank: +30 sigma
        } else bq[it] = -1;
    }
    __syncthreads();

    // block-local exclusive scan of cnt[0..1023]: 4 slots/thread + wave scan
    int t4 = tid << 2;
    int c0 = cnt[t4], c1 = cnt[t4 + 1], c2 = cnt[t4 + 2], c3 = cnt[t4 + 3];
    int s4 = c0 + c1 + c2 + c3;
    int v = s4;
    #pragma unroll
    for (int off = 1; off < 64; off <<= 1) {
        int t = __shfl_up(v, off, 64);
        if ((tid & 63) >= off) v += t;
    }
    if ((tid & 63) == 63) wsum[tid >> 6] = v;
    __syncthreads();
    if (tid == 0) {
        int a = 0;
        #pragma unroll
        for (int w = 0; w < 4; ++w) { wbase[w] = a; a += wsum[w]; }
    }
    __syncthreads();
    int base = wbase[tid >> 6] + (v - s4);
    offs[t4]     = base;
    offs[t4 + 1] = base + c0;
    offs[t4 + 2] = base + c0 + c1;
    offs[t4 + 3] = base + c0 + c1 + c2;
    __syncthreads();

    int NBv = (N + BNODES - 1) >> BSHIFT;             // 782
    for (int i = tid; i <= NBv; i += 256)             // transposed table write
        boffT[(size_t)i * nbinp + blockIdx.x] = offs[i];

    #pragma unroll
    for (int it = 0; it < EPB; ++it) {         // pass 2: slab scatter (16KB window)
        int q = bq[it];
        if (q >= 0) {
            int pos = offs[q >> 9] + (q & 511);
            ebuf[tstart + pos] = rec[it];
        }
    }
}

// ---------------- Aggregate: parallel pack + LDS counting-sort + walk --------
// One 512-thread block per bucket, XCD-chunked bucket swizzle.
// Walk de-fattened vs R7 (VALUBusy 38.6% = issue-bound): node segments are
// padded to 4-record alignment so dn comes via ds_read_b128 broadcasts (was
// 8x ds_read_b32), and the denominator is lane-distributed (lane l<8 loads
// es2 for edge l; 3x shfl_xor + broadcast at slot end) instead of 32 lanes
// redundantly loading/adding every ev. ~70 -> ~45 insts per 8 edges.
// All LDS atomics INTEGER (fp32 LDS atomics = CAS loops, proven R3/R5).
__global__ __launch_bounds__(512) void gat_aggregate(
    const __half* __restrict__ g16, const float* __restrict__ es2,
    const unsigned* __restrict__ ebuf, const int* __restrict__ boffT,
    float* __restrict__ out, int N, int nbin, int nbinp)
{
    __shared__ unsigned srt[SRTCAP];     // 13.5 KB node-sorted dst (4-aligned segs)
    __shared__ unsigned srca[CAP];       // 12 KB gather addresses
    __shared__ int cnt[BNODES];
    __shared__ int basep[BNODES];
    __shared__ int pos2[BNODES];
    __shared__ int wsum[8], wbase[8], totsh;
    int tid = threadIdx.x;

    // bijective XCD-chunked swizzle (m204): XCD k owns a contiguous bk range
    int nwg = gridDim.x;
    int xcd = blockIdx.x & 7;
    int q = nwg >> 3, rr = nwg & 7;
    int bk = (xcd < rr ? xcd * (q + 1) : rr * (q + 1) + (xcd - rr) * q)
           + ((int)blockIdx.x >> 3);

    if (tid < BNODES) { cnt[tid] = 0; pos2[tid] = 0; }

    // per-block run for this bucket: two COALESCED boffT row reads
    int rstart = 0, rlen = 0;
    if (tid < nbin) {
        rstart = boffT[(size_t)bk * nbinp + tid];
        rlen   = boffT[(size_t)(bk + 1) * nbinp + tid] - rstart;
    }
    int v = rlen;                                    // scan run lengths
    #pragma unroll
    for (int off = 1; off < 64; off <<= 1) {
        int t = __shfl_up(v, off, 64);
        if ((tid & 63) >= off) v += t;
    }
    if ((tid & 63) == 63) wsum[tid >> 6] = v;
    __syncthreads();
    if (tid == 0) {
        int a = 0;
        #pragma unroll
        for (int w = 0; w < 8; ++w) { wbase[w] = a; a += wsum[w]; }
        totsh = a;
    }
    __syncthreads();
    int dest = wbase[tid >> 6] + (v - rlen);         // exclusive pack offset
    int lim = CAP - dest; if (lim < 0) lim = 0;      // defensive (never fires)
    if (rlen > lim) rlen = lim;
    {
        unsigned abase = (unsigned)tid * TILE + (unsigned)rstart;
        for (int j = 0; j < rlen; ++j)               // LDS-only short loop
            srca[dest + j] = abase + (unsigned)j;
    }
    __syncthreads();
    int cntb = totsh; if (cntb > CAP) cntb = CAP;

    // parallel record fetch (coalesced-by-run) + node histogram
    unsigned held[6];                                // CAP/512 = 6, static idx
    #pragma unroll
    for (int k = 0; k < 6; ++k) {
        int r = tid + (k << 9);
        held[k] = 0xFFFFFFFFu;
        if (r < cntb) held[k] = ebuf[(size_t)srca[r]];
    }
    #pragma unroll
    for (int k = 0; k < 6; ++k) {
        unsigned u = held[k];
        if (u != 0xFFFFFFFFu) atomicAdd(&cnt[u >> 17], 1);   // native ds_add
    }
    __syncthreads();

    if (tid < 64) {                                  // single-wave 128-scan
        int a = cnt[2 * tid], b2 = cnt[2 * tid + 1];
        int pa = (a + 3) & ~3, pb = (b2 + 3) & ~3;   // 4-align each segment
        int s = pa + pb;
        int vv = s;
        #pragma unroll
        for (int off = 1; off < 64; off <<= 1) {
            int t = __shfl_up(vv, off, 64);
            if (tid >= off) vv += t;
        }
        int excl = vv - s;
        basep[2 * tid]     = excl;
        basep[2 * tid + 1] = excl + pa;
    }
    __syncthreads();

    #pragma unroll
    for (int k = 0; k < 6; ++k) {                    // scatter into node order
        unsigned u = held[k];
        if (u != 0xFFFFFFFFu) {
            int sl = (int)(u >> 17);
            int p = basep[sl] + atomicAdd(&pos2[sl], 1);
            srt[p] = u & 0x1FFFFu;
        }
    }
    __syncthreads();

    int unit = tid >> 5, col = tid & 31;             // 16 units x 32 lanes
    int lane64 = tid & 63;
    for (int sl = unit; sl < BNODES; sl += 16) {
        long node = (long)bk * BNODES + sl;
        if (node >= N) break;
        float acc = __half2float(g16[node * DOUT + col]);  // self-loop
        float selfe = es2[node];
        float dpart = 0.f;
        int e = basep[sl], e_end = basep[sl] + cnt[sl];    // e is 4-aligned

        while (e + 8 <= e_end) {                     // 8-way independent gathers
            uint4 q0 = *(const uint4*)&srt[e];       // ds_read_b128 broadcast
            uint4 q1 = *(const uint4*)&srt[e + 4];
            float evp = 0.f;
            if (col < 8) evp = es2[srt[e + col]];    // lane-distributed denom
            int dn[8] = {(int)q0.x, (int)q0.y, (int)q0.z, (int)q0.w,
                         (int)q1.x, (int)q1.y, (int)q1.z, (int)q1.w};
            unsigned short gv[8];
            #pragma unroll
            for (int j = 0; j < 8; ++j)
                gv[j] = *(const unsigned short*)&g16[(long)dn[j] * DOUT + col];
            dpart += evp;
            #pragma unroll
            for (int j = 0; j < 8; ++j)
                acc += __half2float(*(const __half*)&gv[j]);
            e += 8;
        }
        while (e + 4 <= e_end) {                     // 4-way tail (still aligned)
            uint4 q0 = *(const uint4*)&srt[e];
            float evp = 0.f;
            if (col < 4) evp = es2[srt[e + col]];
            int dn[4] = {(int)q0.x, (int)q0.y, (int)q0.z, (int)q0.w};
            unsigned short gv[4];
            #pragma unroll
            for (int j = 0; j < 4; ++j)
                gv[j] = *(const unsigned short*)&g16[(long)dn[j] * DOUT + col];
            dpart += evp;
            #pragma unroll
            for (int j = 0; j < 4; ++j)
                acc += __half2float(*(const __half*)&gv[j]);
            e += 4;
        }
        for (; e < e_end; ++e) {                     // scalar tail (<=3)
            int dn = (int)srt[e];
            acc += __half2float(g16[(long)dn * DOUT + col]);
            if (col == 0) dpart += es2[dn];
        }
        #pragma unroll
        for (int off = 1; off < 8; off <<= 1)        // sum lanes 0..7
            dpart += __shfl_xor(dpart, off, 64);
        float dtot = __shfl(dpart, lane64 & 32, 64); // broadcast unit-lane0
        out[node * DOUT + col] = acc / (selfe + dtot);
    }
}

extern "C" void kernel_launch(void* const* d_in, const int* in_sizes, int n_in,
                              void* d_out, int out_size, void* d_ws, size_t ws_size,
                              hipStream_t stream)
{
    const float* x  = (const float*)d_in[0];
    const int*   ei = (const int*)d_in[1];
    const float* W  = (const float*)d_in[2];
    const float* b  = (const float*)d_in[3];
    // d_in[4] = a1_w: unused — s1 cancels inside the segment softmax.
    const float* a2 = (const float*)d_in[5];
    float* out = (float*)d_out;

    int N = in_sizes[0] / DIN;
    int E = in_sizes[1] / 2;
    const int* src = ei;
    const int* dst = ei + E;

    int NB = (N + BNODES - 1) >> BSHIFT;      // 782
    int nbin = (E + TILE - 1) / TILE;         // 391 bin blocks
    int nbinp = (nbin + 7) & ~7;              // 392 (row pitch, coalescing pad)

    char* ws = (char*)d_ws;
    __half*   g16   = (__half*)ws;  ws += (size_t)N * DOUT * sizeof(__half);
    float*    es2   = (float*)ws;   ws += (size_t)N * sizeof(float);
    int*      boffT = (int*)ws;     ws += (size_t)(NB + 1) * nbinp * sizeof(int);
    unsigned* ebuf  = (unsigned*)ws; ws += (size_t)nbin * TILE * sizeof(unsigned);

    int ntiles = (N + 15) / 16;               // 6250
    int nwaves = (ntiles + TPW - 1) / TPW;    // 1563 linear waves
    int nlin   = (nwaves + 3) / 4;            // 391 linear blocks (4 waves)

    gat_fused    <<<nbin + nlin, 256, 0, stream>>>(x, W, b, a2, src, dst,
                                                   g16, es2, ebuf, boffT,
                                                   N, E, ntiles, nbin, nbinp);
    gat_aggregate<<<NB, 512, 0, stream>>>(g16, es2, ebuf, boffT, out, N,
                                          nbin, nbinp);
}

// Round 10
// 147.535 us; speedup vs baseline: 1.0512x; 1.0512x over previous
//
#include <hip/hip_runtime.h>
#include <hip/hip_fp16.h>

#define DIN 128
#define DOUT 32
#define SLOPE 0.2f

#define BSHIFT 7                 // 128 nodes per bucket
#define BNODES 128
#define NBS    1024              // scan width (>= 782 buckets, pow2)
#define CAP    3072              // record capacity (lambda 2046, +22 sigma)
#define SRTCAP (CAP + 384)       // node-sorted array, 4-aligned segments
#define TILE   4096              // edges per bin block (391 bin blocks)
#define EPB    (TILE / 256)      // edges per thread (16)

// fused-kernel shared overlay: bin role needs 8224 B, linear role 16384 B
#define FSMEM  16384

typedef short s16x8 __attribute__((ext_vector_type(8)));   // 8 bf16 (4 VGPRs)
typedef float f32x4 __attribute__((ext_vector_type(4)));   // MFMA C/D frag

__device__ __forceinline__ short f2bf(float f) {          // fp32 -> bf16 (RNE)
    unsigned u = __float_as_uint(f);
    return (short)((u + 0x7fffu + ((u >> 16) & 1u)) >> 16);
}
__device__ __forceinline__ float bf2f(short s) {
    return __uint_as_float(((unsigned)(unsigned short)s) << 16);
}

// ---------------- Linear tile: one wave = 16 rows of h via MFMA --------------
// W fragments come from the block-shared LDS planes (Whi/Wlo, XOR-swizzled):
// NO per-wave W load/convert (R6 proved conversion was the linear-role cost;
// staging it per-block removes the 4x-amortized remainder AND frees TPW=1 ->
// 6250 independent waves, ~30 waves/CU vs R7's 12). hi/lo split both sides,
// 3 MFMAs per k-chunk => fp32-level accuracy.
__device__ __forceinline__ void linear_tile(
    int tile, int ntiles, int lane, int N,
    const unsigned short* __restrict__ Whi, const unsigned short* __restrict__ Wlo,
    const float* __restrict__ x,
    const float* __restrict__ b, const float* __restrict__ a2,
    __half* __restrict__ g16, float* __restrict__ es2)
{
    if (tile >= ntiles) return;
    int m = lane & 15, oct = lane >> 4;

    s16x8 bh[2][4], bl[2][4];                  // ds_read_b128 x16, bank-balanced
    #pragma unroll
    for (int t = 0; t < 2; ++t) {
        int row = t * 16 + m;                  // row & 15 == m
        #pragma unroll
        for (int kc = 0; kc < 4; ++kc) {
            int sch = (kc * 4 + oct) ^ m;      // XOR swizzle (matches writes)
            bh[t][kc] = *(const s16x8*)((const char*)Whi + row * 256 + sch * 16);
            bl[t][kc] = *(const s16x8*)((const char*)Wlo + row * 256 + sch * 16);
        }
    }

    int c0 = m, c1 = 16 + m;
    float b0 = b[c0], b1 = b[c1], A0 = a2[c0], A1 = a2[c1];

    long rowbase = (long)tile * 16;
    long lrow = rowbase + m; if (lrow > N - 1) lrow = N - 1;   // load clamp
    const float* xrow = x + lrow * DIN + oct * 8;
    f32x4 acc0 = {0.f, 0.f, 0.f, 0.f}, acc1 = {0.f, 0.f, 0.f, 0.f};
    #pragma unroll
    for (int kc = 0; kc < 4; ++kc) {
        float4 x0 = *(const float4*)(xrow + kc * 32);
        float4 x1 = *(const float4*)(xrow + kc * 32 + 4);
        float xf[8] = {x0.x, x0.y, x0.z, x0.w, x1.x, x1.y, x1.z, x1.w};
        s16x8 ah, al;
        #pragma unroll
        for (int j = 0; j < 8; ++j) {
            short hh = f2bf(xf[j]);
            ah[j] = hh;
            al[j] = f2bf(xf[j] - bf2f(hh));
        }
        acc0 = __builtin_amdgcn_mfma_f32_16x16x32_bf16(al, bh[0][kc], acc0, 0, 0, 0);
        acc0 = __builtin_amdgcn_mfma_f32_16x16x32_bf16(ah, bl[0][kc], acc0, 0, 0, 0);
        acc0 = __builtin_amdgcn_mfma_f32_16x16x32_bf16(ah, bh[0][kc], acc0, 0, 0, 0);
        acc1 = __builtin_amdgcn_mfma_f32_16x16x32_bf16(al, bh[1][kc], acc1, 0, 0, 0);
        acc1 = __builtin_amdgcn_mfma_f32_16x16x32_bf16(ah, bl[1][kc], acc1, 0, 0, 0);
        acc1 = __builtin_amdgcn_mfma_f32_16x16x32_bf16(ah, bh[1][kc], acc1, 0, 0, 0);
    }

    float hv0[4], hv1[4], sp[4];
    #pragma unroll
    for (int i = 0; i < 4; ++i) {
        hv0[i] = acc0[i] + b0;
        hv1[i] = acc1[i] + b1;
        float z0 = hv0[i] > 0.f ? hv0[i] : SLOPE * hv0[i];
        float z1 = hv1[i] > 0.f ? hv1[i] : SLOPE * hv1[i];
        sp[i] = z0 * A0 + z1 * A1;
    }
    #pragma unroll
    for (int off = 1; off <= 8; off <<= 1) {
        #pragma unroll
        for (int i = 0; i < 4; ++i) sp[i] += __shfl_xor(sp[i], off, 64);
    }
    #pragma unroll
    for (int i = 0; i < 4; ++i) {
        long r = rowbase + oct * 4 + i;
        if (r >= N) continue;
        float ev = __expf(sp[i]);              // shift-invariant softmax: no max pass
        g16[r * DOUT + c0] = __float2half(ev * hv0[i]);
        g16[r * DOUT + c1] = __float2half(ev * hv1[i]);
        if (m == 0) es2[r] = ev;
    }
}

// ---------------- Fused kernel: bin blocks FIRST, linear blocks fill in ------
// Bin role (blocks < nbin): ZERO global atomics (verified R4) — counting-sort
// TILE edges into the block's PRIVATE slab + transposed offset table boffT.
// Linear role: cooperative W->LDS conversion (once per block), then 4 waves
// each compute ONE 16-row tile.
__global__ __launch_bounds__(256) void gat_fused(
    const float* __restrict__ x, const float* __restrict__ W,
    const float* __restrict__ b, const float* __restrict__ a2,
    const int* __restrict__ src, const int* __restrict__ dst,
    __half* __restrict__ g16, float* __restrict__ es2,
    unsigned* __restrict__ ebuf, int* __restrict__ boffT,
    int N, int E, int ntiles, int nbin, int nbinp)
{
    __shared__ __align__(16) unsigned char smem[FSMEM];
    int tid = threadIdx.x;

    if ((int)blockIdx.x >= nbin) {
        // -------- linear role: stage W (hi/lo bf16, XOR-swizzled) in LDS -----
        unsigned short* Whi = (unsigned short*)smem;           // [32][128]
        unsigned short* Wlo = (unsigned short*)(smem + 8192);  // [32][128]
        for (int c = tid; c < 512; c += 256) {   // 512 chunks of 8 elements
            int row = c >> 4, ch = c & 15;
            const float* wsrc = W + (long)row * DIN + ch * 8;
            float4 a  = *(const float4*)wsrc;
            float4 b4 = *(const float4*)(wsrc + 4);
            float wf[8] = {a.x, a.y, a.z, a.w, b4.x, b4.y, b4.z, b4.w};
            s16x8 hi, lo;
            #pragma unroll
            for (int j = 0; j < 8; ++j) {
                short hh = f2bf(wf[j]);
                hi[j] = hh;
                lo[j] = f2bf(wf[j] - bf2f(hh));
            }
            int sch = ch ^ (row & 15);           // swizzle (read side matches)
            *(s16x8*)((char*)Whi + row * 256 + sch * 16) = hi;
            *(s16x8*)((char*)Wlo + row * 256 + sch * 16) = lo;
        }
        __syncthreads();
        int wave = tid >> 6;
        int tile = ((int)blockIdx.x - nbin) * 4 + wave;
        linear_tile(tile, ntiles, tid & 63, N, Whi, Wlo, x, b, a2, g16, es2);
        return;
    }

    // -------- bin role (verbatim R4/R8) --------
    int* cnt   = (int*)smem;                     // [1024]
    int* offs  = (int*)(smem + 4096);            // [1024]
    int* wsum  = (int*)(smem + 8192);            // [4]
    int* wbase = (int*)(smem + 8208);            // [4]
    long tstart = (long)blockIdx.x * TILE;

    for (int i = tid; i < NBS; i += 256) cnt[i] = 0;
    __syncthreads();

    unsigned rec[EPB];     // packed record (slot<<17 | dst)
    int      bq[EPB];      // bk<<9 | rank  (per-block per-bucket rank)
    #pragma unroll
    for (int it = 0; it < EPB; ++it) {           // pass 1: histogram + rank
        long e = tstart + it * 256 + tid;
        int s = (e < E) ? src[e] : -1;
        int d = (e < E) ? dst[e] : 0;            // prefetch (latency hides here)
        if (s >= 0) {
            int bk = s >> BSHIFT;
            int rv = atomicAdd(&cnt[bk], 1);     // native ds_add_rtn_u32
            rec[it] = ((unsigned)(s & (BNODES - 1)) << 17) | (unsigned)d;
            bq[it] = (rv < 511) ? ((bk << 9) | rv) : -1;   // 9-bit rank: +30 sigma
        } else bq[it] = -1;
    }
    __syncthreads();

    // block-local exclusive scan of cnt[0..1023]: 4 slots/thread + wave scan
    int t4 = tid << 2;
    int c0 = cnt[t4], c1 = cnt[t4 + 1], c2 = cnt[t4 + 2], c3 = cnt[t4 + 3];
    int s4 = c0 + c1 + c2 + c3;
    int v = s4;
    #pragma unroll
    for (int off = 1; off < 64; off <<= 1) {
        int t = __shfl_up(v, off, 64);
        if ((tid & 63) >= off) v += t;
    }
    if ((tid & 63) == 63) wsum[tid >> 6] = v;
    __syncthreads();
    if (tid == 0) {
        int a = 0;
        #pragma unroll
        for (int w = 0; w < 4; ++w) { wbase[w] = a; a += wsum[w]; }
    }
    __syncthreads();
    int base = wbase[tid >> 6] + (v - s4);
    offs[t4]     = base;
    offs[t4 + 1] = base + c0;
    offs[t4 + 2] = base + c0 + c1;
    offs[t4 + 3] = base + c0 + c1 + c2;
    __syncthreads();

    int NBv = (N + BNODES - 1) >> BSHIFT;        // 782
    for (int i = tid; i <= NBv; i += 256)        // transposed table write
        boffT[(size_t)i * nbinp + blockIdx.x] = offs[i];

    #pragma unroll
    for (int it = 0; it < EPB; ++it) {           // pass 2: slab scatter (16KB win)
        int q = bq[it];
        if (q >= 0) {
            int pos = offs[q >> 9] + (q & 511);
            ebuf[tstart + pos] = rec[it];
        }
    }
}

// ---------------- Aggregate: parallel pack + LDS counting-sort + walk --------
// R8 verbatim (verified, 41us). One 512-thread block per bucket, XCD-chunked
// bucket swizzle; parallel record fetch; single-wave 128-scan with 4-aligned
// segments; 16x32 walk with ds_read_b128 dn-broadcasts and lane-distributed
// denominator. All LDS atomics INTEGER (fp32 LDS atomics = CAS loops, R3/R5).
__global__ __launch_bounds__(512) void gat_aggregate(
    const __half* __restrict__ g16, const float* __restrict__ es2,
    const unsigned* __restrict__ ebuf, const int* __restrict__ boffT,
    float* __restrict__ out, int N, int nbin, int nbinp)
{
    __shared__ unsigned srt[SRTCAP];     // 13.5 KB node-sorted dst (4-aligned segs)
    __shared__ unsigned srca[CAP];       // 12 KB gather addresses
    __shared__ int cnt[BNODES];
    __shared__ int basep[BNODES];
    __shared__ int pos2[BNODES];
    __shared__ int wsum[8], wbase[8], totsh;
    int tid = threadIdx.x;

    // bijective XCD-chunked swizzle (m204): XCD k owns a contiguous bk range
    int nwg = gridDim.x;
    int xcd = blockIdx.x & 7;
    int q = nwg >> 3, rr = nwg & 7;
    int bk = (xcd < rr ? xcd * (q + 1) : rr * (q + 1) + (xcd - rr) * q)
           + ((int)blockIdx.x >> 3);

    if (tid < BNODES) { cnt[tid] = 0; pos2[tid] = 0; }

    // per-block run for this bucket: two COALESCED boffT row reads
    int rstart = 0, rlen = 0;
    if (tid < nbin) {
        rstart = boffT[(size_t)bk * nbinp + tid];
        rlen   = boffT[(size_t)(bk + 1) * nbinp + tid] - rstart;
    }
    int v = rlen;                                    // scan run lengths
    #pragma unroll
    for (int off = 1; off < 64; off <<= 1) {
        int t = __shfl_up(v, off, 64);
        if ((tid & 63) >= off) v += t;
    }
    if ((tid & 63) == 63) wsum[tid >> 6] = v;
    __syncthreads();
    if (tid == 0) {
        int a = 0;
        #pragma unroll
        for (int w = 0; w < 8; ++w) { wbase[w] = a; a += wsum[w]; }
        totsh = a;
    }
    __syncthreads();
    int dest = wbase[tid >> 6] + (v - rlen);         // exclusive pack offset
    int lim = CAP - dest; if (lim < 0) lim = 0;      // defensive (never fires)
    if (rlen > lim) rlen = lim;
    {
        unsigned abase = (unsigned)tid * TILE + (unsigned)rstart;
        for (int j = 0; j < rlen; ++j)               // LDS-only short loop
            srca[dest + j] = abase + (unsigned)j;
    }
    __syncthreads();
    int cntb = totsh; if (cntb > CAP) cntb = CAP;

    // parallel record fetch (coalesced-by-run) + node histogram
    unsigned held[6];                                // CAP/512 = 6, static idx
    #pragma unroll
    for (int k = 0; k < 6; ++k) {
        int r = tid + (k << 9);
        held[k] = 0xFFFFFFFFu;
        if (r < cntb) held[k] = ebuf[(size_t)srca[r]];
    }
    #pragma unroll
    for (int k = 0; k < 6; ++k) {
        unsigned u = held[k];
        if (u != 0xFFFFFFFFu) atomicAdd(&cnt[u >> 17], 1);   // native ds_add
    }
    __syncthreads();

    if (tid < 64) {                                  // single-wave 128-scan
        int a = cnt[2 * tid], b2 = cnt[2 * tid + 1];
        int pa = (a + 3) & ~3, pb = (b2 + 3) & ~3;   // 4-align each segment
        int s = pa + pb;
        int vv = s;
        #pragma unroll
        for (int off = 1; off < 64; off <<= 1) {
            int t = __shfl_up(vv, off, 64);
            if (tid >= off) vv += t;
        }
        int excl = vv - s;
        basep[2 * tid]     = excl;
        basep[2 * tid + 1] = excl + pa;
    }
    __syncthreads();

    #pragma unroll
    for (int k = 0; k < 6; ++k) {                    // scatter into node order
        unsigned u = held[k];
        if (u != 0xFFFFFFFFu) {
            int sl = (int)(u >> 17);
            int p = basep[sl] + atomicAdd(&pos2[sl], 1);
            srt[p] = u & 0x1FFFFu;
        }
    }
    __syncthreads();

    int unit = tid >> 5, col = tid & 31;             // 16 units x 32 lanes
    int lane64 = tid & 63;
    for (int sl = unit; sl < BNODES; sl += 16) {
        long node = (long)bk * BNODES + sl;
        if (node >= N) break;
        float acc = __half2float(g16[node * DOUT + col]);  // self-loop
        float selfe = es2[node];
        float dpart = 0.f;
        int e = basep[sl], e_end = basep[sl] + cnt[sl];    // e is 4-aligned

        while (e + 8 <= e_end) {                     // 8-way independent gathers
            uint4 q0 = *(const uint4*)&srt[e];       // ds_read_b128 broadcast
            uint4 q1 = *(const uint4*)&srt[e + 4];
            float evp = 0.f;
            if (col < 8) evp = es2[srt[e + col]];    // lane-distributed denom
            int dn[8] = {(int)q0.x, (int)q0.y, (int)q0.z, (int)q0.w,
                         (int)q1.x, (int)q1.y, (int)q1.z, (int)q1.w};
            unsigned short gv[8];
            #pragma unroll
            for (int j = 0; j < 8; ++j)
                gv[j] = *(const unsigned short*)&g16[(long)dn[j] * DOUT + col];
            dpart += evp;
            #pragma unroll
            for (int j = 0; j < 8; ++j)
                acc += __half2float(*(const __half*)&gv[j]);
            e += 8;
        }
        while (e + 4 <= e_end) {                     // 4-way tail (still aligned)
            uint4 q0 = *(const uint4*)&srt[e];
            float evp = 0.f;
            if (col < 4) evp = es2[srt[e + col]];
            int dn[4] = {(int)q0.x, (int)q0.y, (int)q0.z, (int)q0.w};
            unsigned short gv[4];
            #pragma unroll
            for (int j = 0; j < 4; ++j)
                gv[j] = *(const unsigned short*)&g16[(long)dn[j] * DOUT + col];
            dpart += evp;
            #pragma unroll
            for (int j = 0; j < 4; ++j)
                acc += __half2float(*(const __half*)&gv[j]);
            e += 4;
        }
        for (; e < e_end; ++e) {                     // scalar tail (<=3)
            int dn = (int)srt[e];
            acc += __half2float(g16[(long)dn * DOUT + col]);
            if (col == 0) dpart += es2[dn];
        }
        #pragma unroll
        for (int off = 1; off < 8; off <<= 1)        // sum lanes 0..7
            dpart += __shfl_xor(dpart, off, 64);
        float dtot = __shfl(dpart, lane64 & 32, 64); // broadcast unit-lane0
        out[node * DOUT + col] = acc / (selfe + dtot);
    }
}

extern "C" void kernel_launch(void* const* d_in, const int* in_sizes, int n_in,
                              void* d_out, int out_size, void* d_ws, size_t ws_size,
                              hipStream_t stream)
{
    const float* x  = (const float*)d_in[0];
    const int*   ei = (const int*)d_in[1];
    const float* W  = (const float*)d_in[2];
    const float* b  = (const float*)d_in[3];
    // d_in[4] = a1_w: unused — s1 cancels inside the segment softmax.
    const float* a2 = (const float*)d_in[5];
    float* out = (float*)d_out;

    int N = in_sizes[0] / DIN;
    int E = in_sizes[1] / 2;
    const int* src = ei;
    const int* dst = ei + E;

    int NB = (N + BNODES - 1) >> BSHIFT;      // 782
    int nbin = (E + TILE - 1) / TILE;         // 391 bin blocks
    int nbinp = (nbin + 7) & ~7;              // 392 (row pitch, coalescing pad)

    char* ws = (char*)d_ws;
    __half*   g16   = (__half*)ws;  ws += (size_t)N * DOUT * sizeof(__half);
    float*    es2   = (float*)ws;   ws += (size_t)N * sizeof(float);
    int*      boffT = (int*)ws;     ws += (size_t)(NB + 1) * nbinp * sizeof(int);
    unsigned* ebuf  = (unsigned*)ws; ws += (size_t)nbin * TILE * sizeof(unsigned);

    int ntiles = (N + 15) / 16;               // 6250
    int nlin   = (ntiles + 3) / 4;            // 1563 linear blocks (1 tile/wave)

    gat_fused    <<<nbin + nlin, 256, 0, stream>>>(x, W, b, a2, src, dst,
                                                   g16, es2, ebuf, boffT,
                                                   N, E, ntiles, nbin, nbinp);
    gat_aggregate<<<NB, 512, 0, stream>>>(g16, es2, ebuf, boffT, out, N,
                                          nbin, nbinp);
}